// Round 4
// baseline (921.400 us; speedup 1.0000x reference)
//
#include <hip/hip_runtime.h>

// Graph-transformer layer, MI355X. N nodes, E edges, H=128, 4 heads x d=32.
// R4: persistent k_edge with async global_load_lds double-buffered staging
// (pre-swizzled source, single vmcnt(0) window per tile), 32-edge tiles,
// 3 blocks/CU; local-neighbor ownership test (no global rowStart reads);
// attnout+FFN fused into k_post (H1 in registers); chunked scan.

typedef __bf16 bf16x8 __attribute__((ext_vector_type(8)));
typedef float f32x4 __attribute__((ext_vector_type(4)));
typedef unsigned short u16x8 __attribute__((ext_vector_type(8)));

#define DEV static __device__ __forceinline__
#define ET 32   // edges per k_edge tile

DEV unsigned short f2b(float f){
  union { float f; unsigned u; } v; v.f = f;
  unsigned r = (v.u + 0x7FFFu + ((v.u >> 16) & 1u)) >> 16;   // RNE
  return (unsigned short)r;
}
DEV float b2f(unsigned short h){
  union { unsigned u; float f; } v; v.u = ((unsigned)h) << 16; return v.f;
}
DEV f32x4 mfma16(bf16x8 a, bf16x8 b, f32x4 c){
  return __builtin_amdgcn_mfma_f32_16x16x32_bf16(a, b, c, 0, 0, 0);
}
DEV u16x8 pack8(float4 a, float4 b){
  u16x8 p;
  p[0]=f2b(a.x); p[1]=f2b(a.y); p[2]=f2b(a.z); p[3]=f2b(a.w);
  p[4]=f2b(b.x); p[5]=f2b(b.y); p[6]=f2b(b.z); p[7]=f2b(b.w);
  return p;
}
DEV float sspf(float x){  // shifted softplus
  return fmaxf(x, 0.f) + log1pf(expf(-fabsf(x))) - 0.69314718055994531f;
}
DEV int idx64probe(const int* __restrict__ ei){
  return (ei[1] | ei[3] | ei[5] | ei[7] | ei[9]) == 0;
}
DEV int ld_row(const int* __restrict__ ei, long eg, long E, int is64, int N){
  int v = is64 ? ei[2*eg] : ei[eg];
  return min(max(v, 0), N - 1);
}
DEV int ld_col(const int* __restrict__ ei, long eg, long E, int is64, int N){
  int v = is64 ? ei[2*(E + eg)] : ei[E + eg];
  return min(max(v, 0), N - 1);
}
DEV unsigned swz(unsigned byteoff, unsigned row){
  return byteoff ^ ((row & 7u) << 4);
}
DEV void gload16(const void* g, void* l){
  __builtin_amdgcn_global_load_lds((const __attribute__((address_space(1))) void*)g,
                                   (__attribute__((address_space(3))) void*)l, 16, 0, 0);
}
DEV void bar_lds(){
  asm volatile("s_waitcnt lgkmcnt(0)" ::: "memory");
  __builtin_amdgcn_s_barrier();
}

// ---- 128x128 MFMA tile helper (nodeprep / post): A in LDS (swizzled) ----
DEV void mma128(const unsigned short* At, const unsigned short* __restrict__ WT,
                int t, f32x4 (&acc)[4][4]){
  const int l = t & 63;
  const int wm = (t >> 7) & 1, wn = (t >> 6) & 1;
#pragma unroll
  for (int m = 0; m < 4; ++m)
#pragma unroll
    for (int n = 0; n < 4; ++n)
      acc[m][n] = f32x4{0.f, 0.f, 0.f, 0.f};
#pragma unroll
  for (int kk = 0; kk < 4; ++kk){
    bf16x8 a[4], b[4];
#pragma unroll
    for (int m = 0; m < 4; ++m){
      int row = wm*64 + m*16 + (l & 15);
      a[m] = *(const bf16x8*)((const char*)At +
              swz((unsigned)(row*256 + kk*64 + ((l >> 4) & 3)*16), (unsigned)row));
    }
#pragma unroll
    for (int n = 0; n < 4; ++n){
      int col = wn*64 + n*16 + (l & 15);
      b[n] = *(const bf16x8*)(WT + col*128 + kk*32 + ((l >> 4) & 3)*8);
    }
#pragma unroll
    for (int m = 0; m < 4; ++m)
#pragma unroll
      for (int n = 0; n < 4; ++n)
        acc[m][n] = mfma16(a[m], b[n], acc[m][n]);
  }
}

// ---- 32x128 MFMA (edge tiles): waves 2M x 2N, each 16 rows x 64 cols ----
DEV void mma32(const unsigned short* Ab, const unsigned short* __restrict__ WT,
               int t, f32x4 (&acc)[4]){
  const int l = t & 63, wid = t >> 6, wm = wid >> 1, wn = wid & 1;
#pragma unroll
  for (int n = 0; n < 4; ++n) acc[n] = f32x4{0.f, 0.f, 0.f, 0.f};
#pragma unroll
  for (int kk = 0; kk < 4; ++kk){
    int row = wm*16 + (l & 15);
    bf16x8 a = *(const bf16x8*)((const char*)Ab +
        swz((unsigned)(row*256 + kk*64 + ((l >> 4) & 3)*16), (unsigned)row));
#pragma unroll
    for (int n = 0; n < 4; ++n){
      int col = wn*64 + n*16 + (l & 15);
      bf16x8 b = *(const bf16x8*)(WT + col*128 + kk*32 + ((l >> 4) & 3)*8);
      acc[n] = mfma16(a, b, acc[n]);
    }
  }
}
DEV void store_acc32(unsigned short* Kt, const f32x4 (&acc)[4], int t){
  const int l = t & 63, wid = t >> 6, wm = wid >> 1, wn = wid & 1;
#pragma unroll
  for (int n = 0; n < 4; ++n)
#pragma unroll
    for (int reg = 0; reg < 4; ++reg){
      int er = wm*16 + ((l >> 4) & 3)*4 + reg;
      int col = wn*64 + n*16 + (l & 15);
      *(unsigned short*)((char*)Kt + swz((unsigned)(er*256 + col*2), (unsigned)er))
          = f2b(acc[n][reg]);
    }
}

__global__ void k_zero(float4* __restrict__ p, long n){
  long i = (long)blockIdx.x * blockDim.x + threadIdx.x;
  const long st = (long)gridDim.x * blockDim.x;
  const float4 z = {0.f, 0.f, 0.f, 0.f};
  for (; i < n; i += st) p[i] = z;
}

// ---- weight prep: fp32 [k][n] -> bf16 [n][k] blobs ----
__global__ void k_wprep(const float* __restrict__ WQ, const float* __restrict__ WK,
                        const float* __restrict__ WV, const float* __restrict__ WO,
                        const float* __restrict__ Wi, const float* __restrict__ Wo2,
                        unsigned short* WQT, unsigned short* WKtT, unsigned short* WKbT,
                        unsigned short* WVtT, unsigned short* WVbT, unsigned short* WOT,
                        unsigned short* WinT, unsigned short* WouT){
  int id = blockIdx.x * 256 + threadIdx.x;
  int n = id >> 7, k = id & 127;
  int d = n * 128 + k;
  WQT[d]  = f2b(WQ[k*128 + n]);
  WKtT[d] = f2b(WK[k*128 + n]);
  WKbT[d] = f2b(WK[(k+128)*128 + n]);
  WVtT[d] = f2b(WV[k*128 + n]);
  WVbT[d] = f2b(WV[(k+128)*128 + n]);
  WOT[d]  = f2b(WO[k*128 + n]);
  WinT[d] = f2b(Wi[k*128 + n]);
  WouT[d] = f2b(Wo2[k*128 + n]);
}

// ---- counting sort by destination row ----
__global__ void k_hist(const int* __restrict__ ei, int* __restrict__ cnt, long E, int N){
  const int is64 = idx64probe(ei);
  long i = (long)blockIdx.x * blockDim.x + threadIdx.x;
  const long st = (long)gridDim.x * blockDim.x;
  for (; i < E; i += st) atomicAdd(&cnt[ld_row(ei, i, E, is64, N)], 1);
}

DEV int wave_incl_scan(int v, int lane){
#pragma unroll
  for (int ofs = 1; ofs < 64; ofs <<= 1){
    int u = __shfl_up(v, ofs, 64);
    if (lane >= ofs) v += u;
  }
  return v;
}

// chunked exclusive scan: cnt -> cursor; also writes edata sentinels
__global__ __launch_bounds__(1024) void k_scan(const int* __restrict__ cnt,
                                               int* __restrict__ cursor,
                                               int4* __restrict__ edata,
                                               long E, int N){
  __shared__ int wsum[16], woff[16];
  const int t = threadIdx.x, lane = t & 63, w = t >> 6;
  const int C = (N + 1023) / 1024;
  const int base = t * C;
  int s = 0;
  for (int j = 0; j < C; ++j) if (base + j < N) s += cnt[base + j];
  int incl = wave_incl_scan(s, lane);
  if (lane == 63) wsum[w] = incl;
  __syncthreads();
  if (t == 0){
    int run = 0;
#pragma unroll
    for (int i = 0; i < 16; ++i){ woff[i] = run; run += wsum[i]; }
  }
  __syncthreads();
  int run = woff[w] + incl - s;
  for (int j = 0; j < C; ++j)
    if (base + j < N){ cursor[base + j] = run; run += cnt[base + j]; }
  // edata sentinels: [0] and [E+1 .. E+36] get row = -2
  if (t < 37){
    long gi = (t == 0) ? 0 : (E + t);
    edata[gi] = make_int4(0, -2, 0, 0);
  }
}

__global__ void k_scatter(const int* __restrict__ ei, int* __restrict__ cursor,
                          int4* __restrict__ edata, long E, int N){
  const int is64 = idx64probe(ei);
  long i = (long)blockIdx.x * blockDim.x + threadIdx.x;
  const long st = (long)gridDim.x * blockDim.x;
  for (; i < E; i += st){
    int r = ld_row(ei, i, E, is64, N);
    int c = ld_col(ei, i, E, is64, N);
    int pos = atomicAdd(&cursor[r], 1);
    edata[1 + (long)pos] = make_int4((int)i, r, c, 0);
  }
}

// ---- node prep: LN1(h_V) -> y ; Q=y@WQ, YK=y@WKbot, YV=y@WVbot (bf16) ----
__global__ __launch_bounds__(256) void k_nodeprep(
    const float* __restrict__ hV, const float* __restrict__ l1s, const float* __restrict__ l1b,
    const unsigned short* __restrict__ WQT, const unsigned short* __restrict__ WKbT,
    const unsigned short* __restrict__ WVbT,
    unsigned short* __restrict__ Qbf, unsigned short* __restrict__ YKbf,
    unsigned short* __restrict__ YVbf, int N){
  __shared__ unsigned short At[128*128];
  __shared__ float ps[256], pss[256];
  __shared__ float scs[128], bis[128];
  const int t = threadIdx.x;
  if (t < 128){ scs[t] = l1s[t]; bis[t] = l1b[t]; }
  const int r0 = blockIdx.x * 128;
  const int rl = t & 127, hf = t >> 7;
  const int r = r0 + rl;
  const float4* xp = (const float4*)(hV + (size_t)r*128 + hf*64);
  float s = 0.f, ss = 0.f;
  if (r < N){
#pragma unroll
    for (int i = 0; i < 16; ++i){
      float4 v = xp[i];
      s  += (v.x + v.y) + (v.z + v.w);
      ss += (v.x*v.x + v.y*v.y) + (v.z*v.z + v.w*v.w);
    }
  }
  ps[t] = s; pss[t] = ss;
  __syncthreads();
  const float mu  = (ps[t] + ps[t ^ 128]) * 0.0078125f;
  const float var = (pss[t] + pss[t ^ 128]) * 0.0078125f - mu*mu;
  const float rs  = rsqrtf(var + 1e-5f);
#pragma unroll
  for (int i = 0; i < 8; ++i){
    const int c = hf*64 + i*8;
    u16x8 p = {0,0,0,0,0,0,0,0};
    if (r < N){
      float4 v0 = xp[2*i], v1 = xp[2*i+1];
      p[0] = f2b((v0.x - mu)*rs*scs[c+0] + bis[c+0]);
      p[1] = f2b((v0.y - mu)*rs*scs[c+1] + bis[c+1]);
      p[2] = f2b((v0.z - mu)*rs*scs[c+2] + bis[c+2]);
      p[3] = f2b((v0.w - mu)*rs*scs[c+3] + bis[c+3]);
      p[4] = f2b((v1.x - mu)*rs*scs[c+4] + bis[c+4]);
      p[5] = f2b((v1.y - mu)*rs*scs[c+5] + bis[c+5]);
      p[6] = f2b((v1.z - mu)*rs*scs[c+6] + bis[c+6]);
      p[7] = f2b((v1.w - mu)*rs*scs[c+7] + bis[c+7]);
    }
    *(u16x8*)((char*)At + swz((unsigned)(rl*256 + c*2), (unsigned)rl)) = p;
  }
  __syncthreads();
  const int l = t & 63, wm = (t >> 7) & 1, wn = (t >> 6) & 1;
  f32x4 acc[4][4];
  for (int g = 0; g < 3; ++g){
    const unsigned short* WT = (g == 0) ? WQT : (g == 1) ? WKbT : WVbT;
    unsigned short* O = (g == 0) ? Qbf : (g == 1) ? YKbf : YVbf;
    mma128(At, WT, t, acc);
#pragma unroll
    for (int m = 0; m < 4; ++m)
#pragma unroll
      for (int reg = 0; reg < 4; ++reg){
        int row = wm*64 + m*16 + ((l >> 4) & 3)*4 + reg;
        int gr = r0 + row;
        if (gr < N){
#pragma unroll
          for (int n = 0; n < 4; ++n){
            int col = wn*64 + n*16 + (l & 15);
            O[(size_t)gr*128 + col] = f2b(acc[m][n][reg]);
          }
        }
      }
  }
}

// ---- persistent fused edge pass, async double-buffered staging ----
__global__ __launch_bounds__(256, 3) void k_edge(
    const float* __restrict__ hE,
    const unsigned short* __restrict__ WKtT, const unsigned short* __restrict__ WVtT,
    const unsigned short* __restrict__ Qbf, const unsigned short* __restrict__ YKbf,
    const unsigned short* __restrict__ YVbf,
    const int4* __restrict__ edata,     // [1 + E + 37], row sentinels at ends
    float* __restrict__ num, float* __restrict__ den,
    long E, long NT){
  __shared__ float4 stage[2][ET*32];          // 2 x 16KB raw fp32 rows
  __shared__ unsigned short Ab[ET*128];       // 8KB bf16 swizzled
  __shared__ unsigned short Kt[ET*128];       // 8KB (K tile, then V tile)
  __shared__ float aS[ET][4];
  __shared__ int4 idxb[3][36];                // {perm,row,col,_} for edges e0-1..e0+34

  const int t = threadIdx.x, l = t & 63, wid = t >> 6;
  const long b0 = blockIdx.x, G = gridDim.x;
  const long ntloc = (b0 < NT) ? ((NT - 1 - b0) / G + 1) : 0;

  auto tileof = [&](long i) -> long {
    long tt = b0 + i * G; return (tt < NT) ? tt : (NT - 1);
  };
  auto issue_idx = [&](long i, int slot){
    long tt = tileof(i);
    if (l < 9)
      gload16((const void*)(edata + tt*ET + (wid*9 + l)), (void*)&idxb[slot][wid*9]);
  };
  auto issue_pf = [&](long i, int buf){
    const int slot = (int)(i % 3);
#pragma unroll
    for (int k = 0; k < 4; ++k){
      int U = (wid*4 + k)*64 + l;          // 0..1023 16B-units
      int row = U >> 5, u = U & 31;
      int pe = idxb[slot][1 + row].x;
      pe = min(max(pe, 0), (int)(E - 1));
      int j = u ^ (row & 7);               // pre-swizzled source unit
      gload16((const void*)(hE + (size_t)pe*128 + j*4),
              (void*)&stage[buf][(wid*4 + k)*64]);
    }
  };

  // prologue: idx(0), idx(1); wait idx(0); pf(0)
  issue_idx(0, 0);
  issue_idx(1, 1);
  asm volatile("s_waitcnt vmcnt(1)" ::: "memory");
  __builtin_amdgcn_sched_barrier(0);
  __builtin_amdgcn_s_barrier();
  issue_pf(0, 0);
  int p = 0;

  for (long it = 0; it < ntloc; ++it){
    const int slot = (int)(it % 3);
    // W: single drain point (stage[p] + idx ready; walk stores retired)
    asm volatile("s_waitcnt vmcnt(0) lgkmcnt(0)" ::: "memory");
    __builtin_amdgcn_sched_barrier(0);
    __builtin_amdgcn_s_barrier();
    // E: convert fp32 stage -> bf16 swizzled Ab
    {
      const int row = t >> 3, s = t & 7;
      float4 f[4];
#pragma unroll
      for (int k = 0; k < 4; ++k)
        f[k] = stage[p][row*32 + ((s*4 + k) ^ (row & 7))];
      *(u16x8*)((char*)Ab + swz((unsigned)(row*256 + s*32), (unsigned)row)) = pack8(f[0], f[1]);
      *(u16x8*)((char*)Ab + swz((unsigned)(row*256 + s*32 + 16), (unsigned)row)) = pack8(f[2], f[3]);
    }
    bar_lds();
    // F: K_top = hE_tile @ WKtop
    { f32x4 acc[4]; mma32(Ab, WKtT, t, acc); store_acc32(Kt, acc, t); }
    bar_lds();
    // G: logits = Q[row] . (K_top + YK[col]) per head; exp -> aS
    {
      const int e = t >> 3, s = t & 7;
      int4 ed = idxb[slot][1 + e];
      int r = ed.y;
      int ra = max(r, 0), ca = max(ed.z, 0);
      const u16x8* qp  = (const u16x8*)(Qbf  + (size_t)ra*128 + s*16);
      const u16x8* ykp = (const u16x8*)(YKbf + (size_t)ca*128 + s*16);
      float pl = 0.f;
#pragma unroll
      for (int k = 0; k < 2; ++k){
        u16x8 q = qp[k], yk = ykp[k];
        u16x8 kv = *(const u16x8*)((const char*)Kt +
            swz((unsigned)(e*256 + s*32 + k*16), (unsigned)e));
#pragma unroll
        for (int j = 0; j < 8; ++j) pl += b2f(q[j]) * (b2f(kv[j]) + b2f(yk[j]));
      }
      float full = pl + __shfl_xor(pl, 1);
      if (!(s & 1)) aS[e][s >> 1] = (r >= 0) ? expf(full) : 0.f;
    }
    bar_lds();
    // H: V_top = hE_tile @ WVtop (overwrites Kt)
    { f32x4 acc[4]; mma32(Ab, WVtT, t, acc); store_acc32(Kt, acc, t); }
    bar_lds();
    // I: V += YV[col]
    {
      const int e = t >> 3, s = t & 7;
      int ca = max(idxb[slot][1 + e].z, 0);
      const u16x8* src = (const u16x8*)(YVbf + (size_t)ca*128 + s*16);
#pragma unroll
      for (int k = 0; k < 2; ++k){
        u16x8* pp = (u16x8*)((char*)Kt + swz((unsigned)(e*256 + s*32 + k*16), (unsigned)e));
        u16x8 a = *pp, b = src[k], o;
#pragma unroll
        for (int j = 0; j < 8; ++j) o[j] = f2b(b2f(a[j]) + b2f(b[j]));
        *pp = o;
      }
    }
    bar_lds();
    // P: open DMA window for next tile (overlaps walk + next W)
    issue_idx(it + 2, (int)((it + 2) % 3));
    issue_pf(it + 1, p ^ 1);
    // J: walk — segment reduce over sorted rows; store iff run == full segment
    {
      const int c = t & 127, half = t >> 7, hh = c >> 5;
      const int eb = half * 16;
      auto rowAt = [&](int x) -> int { return idxb[slot][1 + x].y; }; // x in [-1,32]
      auto flush = [&](int rr, int rsx, int rex, float av, float ad){
        if (rr < 0) return;
        bool own = (rowAt(rsx - 1) != rr) && (rowAt(rex) != rr);
        float* np = num + (size_t)rr*128 + c;
        if (own) *np = av; else atomicAdd(np, av);
        if (c < 4){
          float* dp = den + (size_t)rr*4 + c;
          if (own) *dp = ad; else atomicAdd(dp, ad);
        }
      };
      float accv = 0.f, accd = 0.f;
      int cur = rowAt(eb), rs = eb;
#pragma unroll
      for (int e = eb; e < eb + 16; ++e){
        int r = rowAt(e);
        if (r != cur){ flush(cur, rs, e, accv, accd); cur = r; rs = e; accv = 0.f; accd = 0.f; }
        float a = aS[e][hh];
        accv += a * b2f(*(const unsigned short*)((const char*)Kt +
                  swz((unsigned)(e*256 + c*2), (unsigned)e)));
        if (c < 4) accd += aS[e][c];
      }
      flush(cur, rs, eb + 16, accv, accd);
    }
    p ^= 1;
  }
  asm volatile("s_waitcnt vmcnt(0) lgkmcnt(0)" ::: "memory");
  __builtin_amdgcn_s_barrier();
}

// ---- fused post: h1 = hV + ssp(num/den/sqrt d)@WO ; out = h1 + FFN(LN2(h1)) ----
__global__ __launch_bounds__(256, 2) void k_post(
    const float* __restrict__ hV, const float* __restrict__ num,
    const float* __restrict__ den,
    const unsigned short* __restrict__ WOT, const unsigned short* __restrict__ WinT,
    const unsigned short* __restrict__ WouT,
    const float* __restrict__ l2s, const float* __restrict__ l2b,
    const float* __restrict__ bin, const float* __restrict__ bou,
    float* __restrict__ out, int N){
  __shared__ unsigned short At[128*128];
  __shared__ float ps[128][2], pq[128][2];
  __shared__ float scs[128], bis[128], binS[128], bouS[128];
  const int t = threadIdx.x;
  if (t < 128){ scs[t] = l2s[t]; bis[t] = l2b[t]; binS[t] = bin[t]; bouS[t] = bou[t]; }
  const int r0 = blockIdx.x * 128;
  const int rl = t & 127, hf = t >> 7;
  const int r = r0 + rl;
  const float inv = 0.17677669529663687f;  // 1/sqrt(32)
  float i0 = 0.f, i1 = 0.f;
  if (r < N){
    float d0 = den[(size_t)r*4 + 2*hf], d1 = den[(size_t)r*4 + 2*hf + 1];
    i0 = (d0 > 0.f) ? inv / d0 : 0.f;
    i1 = (d1 > 0.f) ? inv / d1 : 0.f;
  }
  const float4* ap = (const float4*)(num + (size_t)r*128 + hf*64);
#pragma unroll
  for (int i = 0; i < 8; ++i){
    u16x8 p = {0,0,0,0,0,0,0,0};
    if (r < N){
      float sc = (i < 4) ? i0 : i1;
      float4 v0 = ap[2*i], v1 = ap[2*i+1];
      p[0]=f2b(sspf(v0.x*sc)); p[1]=f2b(sspf(v0.y*sc)); p[2]=f2b(sspf(v0.z*sc)); p[3]=f2b(sspf(v0.w*sc));
      p[4]=f2b(sspf(v1.x*sc)); p[5]=f2b(sspf(v1.y*sc)); p[6]=f2b(sspf(v1.z*sc)); p[7]=f2b(sspf(v1.w*sc));
    }
    *(u16x8*)((char*)At + swz((unsigned)(rl*256 + hf*128 + i*16), (unsigned)rl)) = p;
  }
  __syncthreads();
  const int l = t & 63, wm = (t >> 7) & 1, wn = (t >> 6) & 1;
  f32x4 acc[4][4];
  mma128(At, WOT, t, acc);
  // H1 = acc + hV at acc positions (held in registers through the FFN)
  float h1[4][4][4];
#pragma unroll
  for (int m = 0; m < 4; ++m)
#pragma unroll
    for (int reg = 0; reg < 4; ++reg){
      int er = wm*64 + m*16 + ((l >> 4) & 3)*4 + reg;
      int gr = r0 + er;
#pragma unroll
      for (int n = 0; n < 4; ++n){
        int col = wn*64 + n*16 + (l & 15);
        h1[m][n][reg] = acc[m][n][reg] + ((gr < N) ? hV[(size_t)gr*128 + col] : 0.f);
      }
    }
  // LN2 row stats (shuffle over 16 lanes, combine halves via LDS)
#pragma unroll
  for (int m = 0; m < 4; ++m)
#pragma unroll
    for (int reg = 0; reg < 4; ++reg){
      float s = 0.f, q = 0.f;
#pragma unroll
      for (int n = 0; n < 4; ++n){ float v = h1[m][n][reg]; s += v; q += v*v; }
#pragma unroll
      for (int o = 1; o < 16; o <<= 1){ s += __shfl_xor(s, o); q += __shfl_xor(q, o); }
      if ((l & 15) == 0){
        int er = wm*64 + m*16 + ((l >> 4) & 3)*4 + reg;
        ps[er][wn] = s; pq[er][wn] = q;
      }
    }
  __syncthreads();
  // y = LN2(h1) -> At (bf16, swizzled, at acc positions)
#pragma unroll
  for (int m = 0; m < 4; ++m)
#pragma unroll
    for (int reg = 0; reg < 4; ++reg){
      int er = wm*64 + m*16 + ((l >> 4) & 3)*4 + reg;
      float mu  = (ps[er][0] + ps[er][1]) * 0.0078125f;
      float var = (pq[er][0] + pq[er][1]) * 0.0078125f - mu*mu;
      float rsv = rsqrtf(var + 1e-5f);
#pragma unroll
      for (int n = 0; n < 4; ++n){
        int col = wn*64 + n*16 + (l & 15);
        float yv = (h1[m][n][reg] - mu)*rsv*scs[col] + bis[col];
        *(unsigned short*)((char*)At + swz((unsigned)(er*256 + col*2), (unsigned)er)) = f2b(yv);
      }
    }
  __syncthreads();
  mma128(At, WinT, t, acc);
  __syncthreads();   // all reads of At done before overwrite
#pragma unroll
  for (int m = 0; m < 4; ++m)
#pragma unroll
    for (int reg = 0; reg < 4; ++reg){
      int er = wm*64 + m*16 + ((l >> 4) & 3)*4 + reg;
#pragma unroll
      for (int n = 0; n < 4; ++n){
        int col = wn*64 + n*16 + (l & 15);
        float v = acc[m][n][reg] + binS[col];
        *(unsigned short*)((char*)At + swz((unsigned)(er*256 + col*2), (unsigned)er))
            = f2b(fmaxf(v, 0.f));
      }
    }
  __syncthreads();
  mma128(At, WouT, t, acc);
#pragma unroll
  for (int m = 0; m < 4; ++m)
#pragma unroll
    for (int reg = 0; reg < 4; ++reg){
      int er = wm*64 + m*16 + ((l >> 4) & 3)*4 + reg;
      int gr = r0 + er;
      if (gr < N){
#pragma unroll
        for (int n = 0; n < 4; ++n){
          int col = wn*64 + n*16 + (l & 15);
          out[(size_t)gr*128 + col] = acc[m][n][reg] + bouS[col] + h1[m][n][reg];
        }
      }
    }
}

extern "C" void kernel_launch(void* const* d_in, const int* in_sizes, int n_in,
                              void* d_out, int out_size, void* d_ws, size_t ws_size,
                              hipStream_t stream)
{
  const float* hV  = (const float*)d_in[0];
  const float* hE  = (const float*)d_in[1];
  const int*   ei  = (const int*)d_in[2];
  const float* WQ  = (const float*)d_in[3];
  const float* WK  = (const float*)d_in[4];
  const float* WV  = (const float*)d_in[5];
  const float* WO  = (const float*)d_in[6];
  const float* l1s = (const float*)d_in[7];
  const float* l1b = (const float*)d_in[8];
  const float* l2s = (const float*)d_in[9];
  const float* l2b = (const float*)d_in[10];
  const float* Wi  = (const float*)d_in[11];
  const float* bi  = (const float*)d_in[12];
  const float* Wo2 = (const float*)d_in[13];
  const float* bo  = (const float*)d_in[14];
  float* out = (float*)d_out;

  const int  N = in_sizes[0] / 128;
  const long E = (long)in_sizes[1] / 128;
  const long NT = (E + ET - 1) / ET;

  char* ws = (char*)d_ws;
  size_t off = 0;
  auto alloc = [&](size_t b){ size_t o = off; off += (b + 255) & ~(size_t)255; return o; };
  const size_t WB = 128*128*sizeof(unsigned short);
  size_t oWQT = alloc(WB), oWKtT = alloc(WB), oWKbT = alloc(WB);
  size_t oWVtT = alloc(WB), oWVbT = alloc(WB), oWOT = alloc(WB);
  size_t oWinT = alloc(WB), oWouT = alloc(WB);
  size_t oQ    = alloc((size_t)N*128*2);
  size_t oYK   = alloc((size_t)N*128*2);
  size_t oYV   = alloc((size_t)N*128*2);
  size_t oED   = alloc((size_t)(E + 38)*16);
  size_t oCUR  = alloc((size_t)N*4);
  size_t oCNT  = alloc((size_t)N*4);        // zeroed region starts here
  size_t oDEN  = alloc((size_t)N*4*4);
  size_t oNUM  = alloc((size_t)N*128*4);
  size_t zero_bytes = (oNUM + (size_t)N*128*4) - oCNT;

  unsigned short* WQT  = (unsigned short*)(ws + oWQT);
  unsigned short* WKtT = (unsigned short*)(ws + oWKtT);
  unsigned short* WKbT = (unsigned short*)(ws + oWKbT);
  unsigned short* WVtT = (unsigned short*)(ws + oWVtT);
  unsigned short* WVbT = (unsigned short*)(ws + oWVbT);
  unsigned short* WOT  = (unsigned short*)(ws + oWOT);
  unsigned short* WinT = (unsigned short*)(ws + oWinT);
  unsigned short* WouT = (unsigned short*)(ws + oWouT);
  unsigned short* Qbf  = (unsigned short*)(ws + oQ);
  unsigned short* YKbf = (unsigned short*)(ws + oYK);
  unsigned short* YVbf = (unsigned short*)(ws + oYV);
  int4* edata  = (int4*)(ws + oED);
  int* cursor  = (int*)(ws + oCUR);
  int* cnt     = (int*)(ws + oCNT);
  float* den   = (float*)(ws + oDEN);
  float* num   = (float*)(ws + oNUM);

  const int nbN = (N + 127) / 128;
  const int nbe = (int)((E + 255) / 256);
  const int gE  = (int)((NT < 768) ? NT : 768);

  k_zero<<<2048, 256, 0, stream>>>((float4*)(ws + oCNT), (long)(zero_bytes / 16));
  k_wprep<<<64, 256, 0, stream>>>(WQ, WK, WV, WO, Wi, Wo2,
                                  WQT, WKtT, WKbT, WVtT, WVbT, WOT, WinT, WouT);
  k_nodeprep<<<nbN, 256, 0, stream>>>(hV, l1s, l1b, WQT, WKbT, WVbT, Qbf, YKbf, YVbf, N);
  k_hist<<<nbe, 256, 0, stream>>>(ei, cnt, E, N);
  k_scan<<<1, 1024, 0, stream>>>(cnt, cursor, edata, E, N);
  k_scatter<<<nbe, 256, 0, stream>>>(ei, cursor, edata, E, N);
  k_edge<<<gE, 256, 0, stream>>>(hE, WKtT, WVtT, Qbf, YKbf, YVbf,
                                 edata, num, den, E, NT);
  k_post<<<nbN, 256, 0, stream>>>(hV, num, den, WOT, WinT, WouT,
                                  l2s, l2b, bi, bo, out, N);
}